// Round 5
// baseline (5363.722 us; speedup 1.0000x reference)
//
#include <hip/hip_runtime.h>

#define NB 128      // batch
#define NT 8192     // time steps
#define NS 128      // states
#define NE 6        // alphabet

__global__ void __launch_bounds__(128, 1)
hmm_forward_kernel(const int* __restrict__ obs, const float* __restrict__ I,
                   const float* __restrict__ A, const float* __restrict__ Bm,
                   float* __restrict__ out)
{
    __shared__ float4 alpha4[2][NS / 4];   // double-buffered alpha, 16B-aligned
    __shared__ float  Bmt[NE * NS];        // Bm transposed: Bmt[o*NS + s]
    __shared__ int    obs_s[128];          // 128-step obs chunk
    __shared__ float  red[2];              // per-wave partial sums

    const int tid = threadIdx.x;
    const int b   = blockIdx.x;
    const int* obs_row = obs + b * NT;

    // Each thread holds column A[:, tid] in registers.
    // A[i*NS + tid] is coalesced across tid for each i.
    float acol[NS];
#pragma unroll
    for (int i = 0; i < NS; ++i) acol[i] = A[i * NS + tid];

    // Transpose Bm into LDS: Bmt[o*NS + s] = Bm[s*NE + o]
#pragma unroll
    for (int k = 0; k < NE; ++k) Bmt[k * NS + tid] = Bm[tid * NE + k];

    // first obs chunk [0, 128)
    obs_s[tid] = obs_row[tid];
    __syncthreads();

    int cur = 0;
    // t = 0: alpha = I * em_0 (unnormalized)
    {
        int o0 = obs_s[0];
        ((float*)alpha4[0])[tid] = I[tid] * Bmt[o0 * NS + tid];
    }
    __syncthreads();

    float ll = 0.0f;

    auto do_step = [&](int o) {
        const float4* ab = (const float4*)alpha4[cur];
        float acc0 = 0.f, acc1 = 0.f, acc2 = 0.f, acc3 = 0.f;
#pragma unroll
        for (int q = 0; q < NS / 4; ++q) {
            float4 v = ab[q];                       // wave-uniform -> LDS broadcast
            acc0 = fmaf(v.x, acol[4 * q + 0], acc0);
            acc1 = fmaf(v.y, acol[4 * q + 1], acc1);
            acc2 = fmaf(v.z, acol[4 * q + 2], acc2);
            acc3 = fmaf(v.w, acol[4 * q + 3], acc3);
        }
        float an = ((acc0 + acc1) + (acc2 + acc3)) * Bmt[o * NS + tid];
        ((float*)alpha4[cur ^ 1])[tid] = an;        // lane-consecutive write
        __syncthreads();
        cur ^= 1;
    };

    auto rescale = [&]() {
        float v = ((float*)alpha4[cur])[tid];
        float s = v;
#pragma unroll
        for (int off = 32; off > 0; off >>= 1) s += __shfl_xor(s, off);
        if ((tid & 63) == 0) red[tid >> 6] = s;
        __syncthreads();
        float Z = red[0] + red[1];                  // uniform across block
        ll += logf(Z);
        ((float*)alpha4[cur])[tid] = v * (1.0f / Z);
        __syncthreads();
    };

    // steps t = 1..7, then rescale (captures log(Z0*...*Z7))
#pragma unroll
    for (int j = 1; j < 8; ++j) do_step(obs_s[j]);
    rescale();

    // main loop: groups of 8 steps + rescale; obs chunk reload every 128 steps
    for (int g = 8; g < NT; g += 8) {
        if ((g & 127) == 0) {
            obs_s[tid] = obs_row[g + tid];
            __syncthreads();
        }
#pragma unroll
        for (int j = 0; j < 8; ++j) do_step(obs_s[(g + j) & 127]);
        rescale();
    }

    // ll == sum_t log Z_t (telescoped); identical for all threads
    if (tid == 0) out[b] = ll;
}

extern "C" void kernel_launch(void* const* d_in, const int* in_sizes, int n_in,
                              void* d_out, int out_size, void* d_ws, size_t ws_size,
                              hipStream_t stream) {
    (void)in_sizes; (void)n_in; (void)d_ws; (void)ws_size; (void)out_size;
    const int*   obs = (const int*)d_in[0];
    const float* I   = (const float*)d_in[1];
    const float* A   = (const float*)d_in[2];
    const float* Bm  = (const float*)d_in[3];
    float*       out = (float*)d_out;

    hipLaunchKernelGGL(hmm_forward_kernel, dim3(NB), dim3(128), 0, stream,
                       obs, I, A, Bm, out);
}

// Round 6
// 3650.842 us; speedup vs baseline: 1.4692x; 1.4692x over previous
//
#include <hip/hip_runtime.h>

#define NB 128      // batch
#define NT 8192     // time steps
#define NS 128      // states
#define NE 6        // alphabet
#define NMAT 7      // C_0..C_5 = A*diag(e_o)*A, C_6 = A
#define CC_BYTES (NMAT * 32 * NS * 16)   // 7*32*128 float4 = 458752 bytes

// ---------------------------------------------------------------------------
// Precompute Cc[m][q][s] (float4 over rows i=4q..4q+3): C_m[i][s].
// C_m = A * diag(Bm[:,m]) * A  for m<6;  C_6 = A.
// ---------------------------------------------------------------------------
__global__ void __launch_bounds__(128, 1)
hmm_precompute_kernel(const float* __restrict__ A, const float* __restrict__ Bm,
                      float* __restrict__ Cc)
{
    __shared__ float Af[NS * NS];   // 64 KB
    __shared__ float wA[NS * NS];   // 64 KB
    const int s  = threadIdx.x;
    const int m  = blockIdx.x;
    const int ig = blockIdx.y;      // row group [ig*32, ig*32+32)

    for (int r = 0; r < NS; ++r) Af[r * NS + s] = A[r * NS + s];
    __syncthreads();

    if (m < 6) {
        for (int k = 0; k < NS; ++k)
            wA[k * NS + s] = Bm[k * NE + m] * Af[k * NS + s];
        __syncthreads();
        for (int i = ig * 32; i < ig * 32 + 32; ++i) {
            float acc = 0.f;
            for (int k = 0; k < NS; ++k)
                acc = fmaf(Af[i * NS + k], wA[k * NS + s], acc);
            Cc[((m * 32 + (i >> 2)) * NS + s) * 4 + (i & 3)] = acc;
        }
    } else {
        for (int i = ig * 32; i < ig * 32 + 32; ++i)
            Cc[((m * 32 + (i >> 2)) * NS + s) * 4 + (i & 3)] = Af[i * NS + s];
    }
}

// ---------------------------------------------------------------------------
// Main pair-step forward kernel: 256 threads = (state s, K-half h).
// ---------------------------------------------------------------------------
__global__ void __launch_bounds__(256, 1)
hmm_pair_kernel(const int* __restrict__ obs, const float* __restrict__ I,
                const float* __restrict__ Bm, const float4* __restrict__ Cc,
                float* __restrict__ out)
{
    __shared__ float4 alphaB[2][NS / 4];   // double-buffered alpha
    __shared__ float  part[2][NS];         // split-K partials
    __shared__ float  Bt[NE * NS];         // Bm transposed
    __shared__ int    obs_s[258];          // obs chunk (+2 overlap)
    __shared__ float  red[4];

    const int tid = threadIdx.x;
    const int s   = tid & (NS - 1);
    const int h   = tid >> 7;              // K-half: k in [64h, 64h+64)
    const int b   = blockIdx.x;
    const int* orow = obs + b * NT;

    if (tid < NS) {
#pragma unroll
        for (int k = 0; k < NE; ++k) Bt[k * NS + tid] = Bm[tid * NE + k];
    }
    obs_s[tid] = orow[tid];
    if (tid < 2) obs_s[256 + tid] = orow[256 + tid];
    __syncthreads();

    if (tid < NS)
        ((float*)alphaB[0])[tid] = I[tid] * Bt[obs_s[0] * NS + tid];

    // prefetch matrix for macro-step j=1 (t=1) into bufA
    float4 bufA[16], bufB[16];
    {
        const int m0 = obs_s[1];
        const float4* src = Cc + (m0 * 32 + 16 * h) * NS + s;
#pragma unroll
        for (int i = 0; i < 16; ++i) bufA[i] = src[i * NS];
    }
    __syncthreads();

    int   cur = 0;
    float ll  = 0.f;
    int   rs  = 0;

    // One macro-step: alpha_new = (alpha @ C_use) * e[EIDX]; prefetch C_NM into PRE.
#define MACRO_STEP(USE, PRE, EIDX, NM, DORESC)                                 \
    {                                                                          \
        const int nm_ = (NM);                                                  \
        const float4* psrc_ = Cc + (nm_ * 32 + 16 * h) * NS + s;               \
        _Pragma("unroll")                                                      \
        for (int i_ = 0; i_ < 16; ++i_) PRE[i_] = psrc_[i_ * NS];              \
        const float4* ab_ = alphaB[cur] + h * 16;                              \
        float a0_ = 0.f, a1_ = 0.f, a2_ = 0.f, a3_ = 0.f;                      \
        _Pragma("unroll")                                                      \
        for (int q_ = 0; q_ < 16; ++q_) {                                      \
            float4 v_ = ab_[q_];            /* wave-uniform LDS broadcast */   \
            a0_ = fmaf(v_.x, USE[q_].x, a0_);                                  \
            a1_ = fmaf(v_.y, USE[q_].y, a1_);                                  \
            a2_ = fmaf(v_.z, USE[q_].z, a2_);                                  \
            a3_ = fmaf(v_.w, USE[q_].w, a3_);                                  \
        }                                                                      \
        part[h][s] = (a0_ + a1_) + (a2_ + a3_);                                \
        __syncthreads();                                                       \
        float a_ = (part[0][s] + part[1][s]) * Bt[(EIDX) * NS + s];            \
        if (DORESC) {                                                          \
            float t_ = a_;                                                     \
            _Pragma("unroll")                                                  \
            for (int o_ = 32; o_ > 0; o_ >>= 1) t_ += __shfl_xor(t_, o_);      \
            if ((tid & 63) == 0) red[tid >> 6] = t_;                           \
            __syncthreads();                                                   \
            float Z_ = red[0] + red[1];                                        \
            ll += logf(Z_);                                                    \
            a_ *= (1.0f / Z_);                                                 \
        }                                                                      \
        if (h == 0) ((float*)alphaB[cur ^ 1])[s] = a_;                         \
        __syncthreads();                                                       \
        cur ^= 1;                                                              \
    }

    // chunk c covers macro-steps j in [128c+1, 128c+128]; local jj = j-(128c+1):
    //   matrix idx = obs_s[2jj+1] (consumed via prefetch), e idx = obs_s[2jj+2],
    //   next-step matrix idx = obs_s[2jj+3]  (jj=127 -> obs_s[257], staged)
    for (int c = 0; c < 32; ++c) {
        if (c) {
            obs_s[tid] = orow[256 * c + tid];
            if (tid < 2) {
                int idx = 256 * c + 256 + tid;
                obs_s[256 + tid] = (idx < NT) ? orow[idx] : 0;
            }
            __syncthreads();
        }
        const int npairs = (c < 31) ? 64 : 63;
        for (int p = 0; p < npairs; ++p) {
            const int b2 = 4 * p + 2;
            const bool d1 = ((++rs) & 3) == 0;
            MACRO_STEP(bufA, bufB, obs_s[b2],     obs_s[b2 + 1], d1);
            const bool d2 = ((++rs) & 3) == 0;
            MACRO_STEP(bufB, bufA, obs_s[b2 + 2], obs_s[b2 + 3], d2);
        }
    }
    // last macro-step j=4095 (jj=126 of chunk 31); prefetch A (index 6) for tail
    {
        const bool d = ((++rs) & 3) == 0;
        MACRO_STEP(bufA, bufB, obs_s[254], 6, d);
    }
    // final single step t=8191: alpha @ A, * e, then total sum -> ll
    {
        const float4* ab = alphaB[cur] + h * 16;
        float a0 = 0.f, a1 = 0.f, a2 = 0.f, a3 = 0.f;
#pragma unroll
        for (int q = 0; q < 16; ++q) {
            float4 v = ab[q];
            a0 = fmaf(v.x, bufB[q].x, a0);
            a1 = fmaf(v.y, bufB[q].y, a1);
            a2 = fmaf(v.z, bufB[q].z, a2);
            a3 = fmaf(v.w, bufB[q].w, a3);
        }
        part[h][s] = (a0 + a1) + (a2 + a3);
        __syncthreads();
        float a = (part[0][s] + part[1][s]) * Bt[obs_s[255] * NS + s];
        float t = a;
#pragma unroll
        for (int o = 32; o > 0; o >>= 1) t += __shfl_xor(t, o);
        if ((tid & 63) == 0) red[tid >> 6] = t;
        __syncthreads();
        if (tid == 0) out[b] = ll + logf(red[0] + red[1]);
    }
#undef MACRO_STEP
}

// ---------------------------------------------------------------------------
// Fallback (round-5 kernel) if workspace is too small for Cc.
// ---------------------------------------------------------------------------
__global__ void __launch_bounds__(128, 1)
hmm_forward_fallback(const int* __restrict__ obs, const float* __restrict__ I,
                     const float* __restrict__ A, const float* __restrict__ Bm,
                     float* __restrict__ out)
{
    __shared__ float4 alpha4[2][NS / 4];
    __shared__ float  Bmt[NE * NS];
    __shared__ int    obs_s[128];
    __shared__ float  red[2];

    const int tid = threadIdx.x;
    const int b   = blockIdx.x;
    const int* obs_row = obs + b * NT;

    float acol[NS];
#pragma unroll
    for (int i = 0; i < NS; ++i) acol[i] = A[i * NS + tid];
#pragma unroll
    for (int k = 0; k < NE; ++k) Bmt[k * NS + tid] = Bm[tid * NE + k];
    obs_s[tid] = obs_row[tid];
    __syncthreads();

    int cur = 0;
    ((float*)alpha4[0])[tid] = I[tid] * Bmt[obs_s[0] * NS + tid];
    __syncthreads();
    float ll = 0.0f;

    auto do_step = [&](int o) {
        const float4* ab = (const float4*)alpha4[cur];
        float acc0 = 0.f, acc1 = 0.f, acc2 = 0.f, acc3 = 0.f;
#pragma unroll
        for (int q = 0; q < NS / 4; ++q) {
            float4 v = ab[q];
            acc0 = fmaf(v.x, acol[4 * q + 0], acc0);
            acc1 = fmaf(v.y, acol[4 * q + 1], acc1);
            acc2 = fmaf(v.z, acol[4 * q + 2], acc2);
            acc3 = fmaf(v.w, acol[4 * q + 3], acc3);
        }
        float an = ((acc0 + acc1) + (acc2 + acc3)) * Bmt[o * NS + tid];
        ((float*)alpha4[cur ^ 1])[tid] = an;
        __syncthreads();
        cur ^= 1;
    };
    auto rescale = [&]() {
        float v = ((float*)alpha4[cur])[tid];
        float ssum = v;
#pragma unroll
        for (int off = 32; off > 0; off >>= 1) ssum += __shfl_xor(ssum, off);
        if ((tid & 63) == 0) red[tid >> 6] = ssum;
        __syncthreads();
        float Z = red[0] + red[1];
        ll += logf(Z);
        ((float*)alpha4[cur])[tid] = v * (1.0f / Z);
        __syncthreads();
    };

#pragma unroll
    for (int j = 1; j < 8; ++j) do_step(obs_s[j]);
    rescale();
    for (int g = 8; g < NT; g += 8) {
        if ((g & 127) == 0) {
            obs_s[tid] = obs_row[g + tid];
            __syncthreads();
        }
#pragma unroll
        for (int j = 0; j < 8; ++j) do_step(obs_s[(g + j) & 127]);
        rescale();
    }
    if (tid == 0) out[b] = ll;
}

extern "C" void kernel_launch(void* const* d_in, const int* in_sizes, int n_in,
                              void* d_out, int out_size, void* d_ws, size_t ws_size,
                              hipStream_t stream) {
    (void)in_sizes; (void)n_in; (void)out_size;
    const int*   obs = (const int*)d_in[0];
    const float* I   = (const float*)d_in[1];
    const float* A   = (const float*)d_in[2];
    const float* Bm  = (const float*)d_in[3];
    float*       out = (float*)d_out;

    if (ws_size < (size_t)CC_BYTES) {
        hipLaunchKernelGGL(hmm_forward_fallback, dim3(NB), dim3(128), 0, stream,
                           obs, I, A, Bm, out);
        return;
    }
    float* Cc = (float*)d_ws;
    hipLaunchKernelGGL(hmm_precompute_kernel, dim3(NMAT, 4), dim3(128), 0, stream,
                       A, Bm, Cc);
    hipLaunchKernelGGL(hmm_pair_kernel, dim3(NB), dim3(256), 0, stream,
                       obs, I, Bm, (const float4*)Cc, out);
}

// Round 7
// 3329.695 us; speedup vs baseline: 1.6109x; 1.0964x over previous
//
#include <hip/hip_runtime.h>

#define NB 128      // batch
#define NT 8192     // time steps
#define NS 128      // states
#define NE 6        // alphabet
#define ROWS 16     // batch rows per block
#define RSP 16      // rescale period (telescoping exact; Z^16 >= ~1e-28, safe)

typedef __attribute__((ext_vector_type(8))) short bf16x8;   // 8 bf16 (4 VGPRs)
typedef __attribute__((ext_vector_type(4))) float f32x4;    // MFMA accumulator
typedef __attribute__((ext_vector_type(4))) int   int32x4;

#define MFMA __builtin_amdgcn_mfma_f32_16x16x32_bf16

// fp32 -> bf16, round-to-nearest-even
__device__ __forceinline__ ushort f2bf(float v) {
    unsigned u = __float_as_uint(v);
    u += 0x7fffu + ((u >> 16) & 1u);
    return (ushort)(u >> 16);
}

// XOR swizzle for alpha LDS (bf16 elements): breaks the 16-way bank conflict
// of stride-256B row-major ds_read_b128 (flips byte bits 4-6 = elem bits 3-5;
// 16B alignment of the b128 reads is preserved since k-offsets are 8-aligned).
#define SWZ(r, c) ((((r) * NS) + (c)) ^ (((r) & 7) << 3))

__global__ void __launch_bounds__(256, 1)
hmm_gemm_kernel(const int* __restrict__ obs, const float* __restrict__ I,
                const float* __restrict__ A, const float* __restrict__ Bm,
                float* __restrict__ out)
{
    __shared__ __align__(16) ushort alds[2][ROWS * NS];  // bf16 alpha, dbuf, swizzled
    __shared__ float Bt[NE * NS];                        // emissions transposed
    __shared__ __align__(16) int obs_lds[ROWS][132];     // 128-step chunk, +4 pad
    __shared__ float part[4][ROWS];                      // per-wave row partials
    __shared__ float Zs[ROWS];                           // 1/Z broadcast

    const int tid = threadIdx.x;
    const int w   = tid >> 6;      // wave 0..3 -> output cols [32w, 32w+32)
    const int l   = tid & 63;
    const int h   = l >> 4;        // quarter-wave 0..3
    const int li  = l & 15;
    const int brow0 = blockIdx.x * ROWS;

    // ---- stage Bt: Bt[o*NS + s] = Bm[s*NE + o] ----
    if (tid < NS) {
#pragma unroll
        for (int k = 0; k < NE; ++k) Bt[k * NS + tid] = Bm[tid * NE + k];
    }
    // ---- stage obs chunk 0 (rows x 128 steps) ----
    {
        const int r = tid >> 4, i0 = (tid & 15) * 8;
        const int32x4* g = (const int32x4*)(obs + (size_t)(brow0 + r) * NT + i0);
        *(int32x4*)&obs_lds[r][i0]     = g[0];
        *(int32x4*)&obs_lds[r][i0 + 4] = g[1];
    }
    // ---- A matrix as register-resident B-fragments (bf16) ----
    // bfrag[tile][q] elem j = A[k = 32q + 8h + j][col = 32w + 16*tile + li]
    bf16x8 bfrag[2][4];
#pragma unroll
    for (int tl = 0; tl < 2; ++tl) {
#pragma unroll
        for (int q = 0; q < 4; ++q) {
            const float* src = A + (size_t)(32 * q + 8 * h) * NS + (32 * w + 16 * tl + li);
            bf16x8 f;
#pragma unroll
            for (int j = 0; j < 8; ++j) f[j] = (short)f2bf(src[j * NS]);
            bfrag[tl][q] = f;
        }
    }
    __syncthreads();

    // ---- t = 0: alpha = I * em_0 (unnormalized) ----
    {
        const int r = tid >> 4, c0 = (tid & 15) * 8;
        const int o0 = obs_lds[r][0];
#pragma unroll
        for (int j = 0; j < 8; ++j) {
            const int c = c0 + j;
            alds[0][SWZ(r, c)] = f2bf(I[c] * Bt[o0 * NS + c]);
        }
    }
    __syncthreads();

    float ll  = 0.f;   // per-row loglik, owned by threads tid < ROWS (row = tid)
    int   cur = 0;

    for (int t = 1; t < NT; ++t) {
        if ((t & 127) == 0) {   // next obs chunk
            const int r = tid >> 4, i0 = (tid & 15) * 8;
            const int32x4* g = (const int32x4*)(obs + (size_t)(brow0 + r) * NT + t + i0);
            *(int32x4*)&obs_lds[r][i0]     = g[0];
            *(int32x4*)&obs_lds[r][i0 + 4] = g[1];
            __syncthreads();
        }
        // A-operand fragments: row = li, k = 32q + 8h + [0..7]
        bf16x8 af[4];
#pragma unroll
        for (int q = 0; q < 4; ++q)
            af[q] = *(const bf16x8*)&alds[cur][SWZ(li, 32 * q + 8 * h)];

        // obs + emission gathers (independent of alpha -> overlap MFMA)
        const int tt = t & 127;
        int o[4];
#pragma unroll
        for (int r = 0; r < 4; ++r) o[r] = obs_lds[4 * h + r][tt];

        f32x4 acc[2];
        acc[0] = (f32x4){0.f, 0.f, 0.f, 0.f};
        acc[1] = (f32x4){0.f, 0.f, 0.f, 0.f};
#pragma unroll
        for (int q = 0; q < 4; ++q) {
            acc[0] = MFMA(af[q], bfrag[0][q], acc[0], 0, 0, 0);
            acc[1] = MFMA(af[q], bfrag[1][q], acc[1], 0, 0, 0);
        }

        // epilogue: multiply emissions.  D layout: col = li, row = 4h + reg.
        float vals[2][4];
#pragma unroll
        for (int tl = 0; tl < 2; ++tl) {
            const int c = 32 * w + 16 * tl + li;
#pragma unroll
            for (int r = 0; r < 4; ++r) vals[tl][r] = acc[tl][r] * Bt[o[r] * NS + c];
        }

        const bool resc = ((t & (RSP - 1)) == 0) || (t == NT - 1);
        if (resc) {
            // row sums: reduce 16 lanes (li) per row, then combine 4 waves via LDS
#pragma unroll
            for (int r = 0; r < 4; ++r) {
                float s = vals[0][r] + vals[1][r];
#pragma unroll
                for (int off = 1; off < 16; off <<= 1) s += __shfl_xor(s, off);
                if (li == 0) part[w][4 * h + r] = s;
            }
            __syncthreads();
            if (tid < ROWS) {
                float Z = part[0][tid] + part[1][tid] + part[2][tid] + part[3][tid];
                ll += logf(Z);
                Zs[tid] = 1.0f / Z;
            }
            __syncthreads();
#pragma unroll
            for (int tl = 0; tl < 2; ++tl)
#pragma unroll
                for (int r = 0; r < 4; ++r) vals[tl][r] *= Zs[4 * h + r];
        }

        // write alpha_{t} (bf16, swizzled) into the other buffer
#pragma unroll
        for (int tl = 0; tl < 2; ++tl) {
            const int c = 32 * w + 16 * tl + li;
#pragma unroll
            for (int r = 0; r < 4; ++r)
                alds[cur ^ 1][SWZ(4 * h + r, c)] = f2bf(vals[tl][r]);
        }
        __syncthreads();
        cur ^= 1;
    }

    // final step was a rescale step (t == NT-1), so ll is complete
    if (tid < ROWS) out[brow0 + tid] = ll;
}

extern "C" void kernel_launch(void* const* d_in, const int* in_sizes, int n_in,
                              void* d_out, int out_size, void* d_ws, size_t ws_size,
                              hipStream_t stream) {
    (void)in_sizes; (void)n_in; (void)d_ws; (void)ws_size; (void)out_size;
    const int*   obs = (const int*)d_in[0];
    const float* I   = (const float*)d_in[1];
    const float* A   = (const float*)d_in[2];
    const float* Bm  = (const float*)d_in[3];
    float*       out = (float*)d_out;

    hipLaunchKernelGGL(hmm_gemm_kernel, dim3(NB / ROWS), dim3(256), 0, stream,
                       obs, I, A, Bm, out);
}

// Round 8
// 3062.843 us; speedup vs baseline: 1.7512x; 1.0871x over previous
//
#include <hip/hip_runtime.h>

#define NB 128      // batch
#define NT 8192     // time steps
#define NS 128      // states
#define NE 6        // alphabet
#define ROWS 16     // batch rows per block
#define WAVES 8     // 512 threads, wave w owns output cols [16w, 16w+16)
#define NMAT 7      // C_0..C_5 = A*diag(e_o)*A (bf16), C_6 = A (bf16)
#define CT_BYTES (NMAT * NS * NS * 2)    // 229376

typedef __attribute__((ext_vector_type(8))) short bf16x8;   // 8 bf16 (4 VGPRs)
typedef __attribute__((ext_vector_type(4))) float f32x4;    // MFMA accumulator
typedef __attribute__((ext_vector_type(4))) int   int32x4;

#define MFMA __builtin_amdgcn_mfma_f32_16x16x32_bf16

// fp32 -> bf16, round-to-nearest-even
__device__ __forceinline__ ushort f2bf(float v) {
    unsigned u = __float_as_uint(v);
    u += 0x7fffu + ((u >> 16) & 1u);
    return (ushort)(u >> 16);
}

// XOR swizzle for alpha LDS (bf16 elems): breaks stride-256B bank conflicts,
// preserves 16B alignment of the b128 A-fragment reads (k-offsets 8-aligned).
#define SWZ(r, c) ((((r) * NS) + (c)) ^ (((r) & 7) << 3))

// ---------------------------------------------------------------------------
// Precompute Ct (bf16, transposed: Ct[(m*NS + col)*NS + k] = C_m[k][col]).
// C_m = A * diag(Bm[:,m]) * A for m<6;  C_6 = A.  Grid (7, 4) x 128 threads.
// ---------------------------------------------------------------------------
__global__ void __launch_bounds__(128, 1)
hmm_precompute_kernel(const float* __restrict__ A, const float* __restrict__ Bm,
                      ushort* __restrict__ Ct)
{
    __shared__ float Af[NS * NS];   // 64 KB
    __shared__ float wA[NS * NS];   // 64 KB
    const int s  = threadIdx.x;
    const int m  = blockIdx.x;
    const int ig = blockIdx.y;      // k-row group [ig*32, ig*32+32)

    for (int r = 0; r < NS; ++r) Af[r * NS + s] = A[r * NS + s];
    __syncthreads();

    if (m < 6) {
        for (int k = 0; k < NS; ++k)
            wA[k * NS + s] = Bm[k * NE + m] * Af[k * NS + s];
        __syncthreads();
        for (int i0 = ig * 32; i0 < ig * 32 + 32; i0 += 4) {
            float a0 = 0.f, a1 = 0.f, a2 = 0.f, a3 = 0.f;
            for (int k = 0; k < NS; ++k) {
                const float wv = wA[k * NS + s];          // per-lane column
                a0 = fmaf(Af[(i0 + 0) * NS + k], wv, a0); // broadcast rows
                a1 = fmaf(Af[(i0 + 1) * NS + k], wv, a1);
                a2 = fmaf(Af[(i0 + 2) * NS + k], wv, a2);
                a3 = fmaf(Af[(i0 + 3) * NS + k], wv, a3);
            }
            Ct[(m * NS + s) * NS + i0 + 0] = f2bf(a0);
            Ct[(m * NS + s) * NS + i0 + 1] = f2bf(a1);
            Ct[(m * NS + s) * NS + i0 + 2] = f2bf(a2);
            Ct[(m * NS + s) * NS + i0 + 3] = f2bf(a3);
        }
    } else {
        for (int i = ig * 32; i < ig * 32 + 32; ++i)
            Ct[(6 * NS + s) * NS + i] = f2bf(Af[i * NS + s]);
    }
}

// ---------------------------------------------------------------------------
// Pair-step forward kernel: 512 threads (8 waves), 16 batch rows per block.
// Per pair: acc_s = alpha @ C_s (s=0..5, all in registers), select by o_t1,
// multiply e_{o_t2}, one LDS round-trip + one barrier for TWO time steps.
// ---------------------------------------------------------------------------
__global__ void __launch_bounds__(512, 2)
hmm_pair6_kernel(const int* __restrict__ obs, const float* __restrict__ I,
                 const float* __restrict__ Bm, const ushort* __restrict__ Ct,
                 float* __restrict__ out)
{
    __shared__ __align__(16) ushort alds[2][ROWS * NS];  // bf16 alpha, dbuf, swizzled
    __shared__ float Bt[NE * NS];                        // emissions transposed
    __shared__ __align__(16) int obs_lds[ROWS][132];     // 129 entries used (+overlap)
    __shared__ float part[WAVES][ROWS];                  // per-wave row partials
    __shared__ float Zs[ROWS];                           // 1/Z broadcast

    const int tid = threadIdx.x;
    const int w   = tid >> 6;       // wave -> cols [16w, 16w+16)
    const int l   = tid & 63;
    const int h   = l >> 4;         // quarter-wave
    const int li  = l & 15;
    const int cc  = 16 * w + li;    // this lane's output state column
    const int brow0 = blockIdx.x * ROWS;

    // ---- stage Bt: Bt[o*NS + s] = Bm[s*NE + o] ----
    if (tid < NS) {
#pragma unroll
        for (int k = 0; k < NE; ++k) Bt[k * NS + tid] = Bm[tid * NE + k];
    }
    // ---- stage obs chunk 0 (+ overlap entry 128) ----
    {
        const int r = tid >> 5, ii = (tid & 31) * 4;
        *(int32x4*)&obs_lds[r][ii] =
            *(const int32x4*)(obs + (size_t)(brow0 + r) * NT + ii);
        if (tid < ROWS)
            obs_lds[tid][128] = obs[(size_t)(brow0 + tid) * NT + 128];
    }
    // ---- register-resident B-fragments for the 6 pair matrices + A ----
    // bfrag[s][q] elem j = C_s[k = 32q + 8h + j][col = cc]
    bf16x8 bfrag[6][4];
#pragma unroll
    for (int s = 0; s < 6; ++s)
#pragma unroll
        for (int q = 0; q < 4; ++q)
            bfrag[s][q] = *(const bf16x8*)(Ct + ((s * NS + cc) * NS + 32 * q + 8 * h));
    bf16x8 afinB[4];   // plain A, for the final odd step
#pragma unroll
    for (int q = 0; q < 4; ++q)
        afinB[q] = *(const bf16x8*)(Ct + ((6 * NS + cc) * NS + 32 * q + 8 * h));
    __syncthreads();

    // ---- t = 0: alpha = I * em_0 (unnormalized) ----
    {
        const int r = tid >> 5, c0 = (tid & 31) * 4;
        const int o0 = obs_lds[r][0];
#pragma unroll
        for (int j = 0; j < 4; ++j) {
            const int c = c0 + j;
            alds[0][SWZ(r, c)] = f2bf(I[c] * Bt[o0 * NS + c]);
        }
    }
    __syncthreads();

    float ll  = 0.f;   // valid on threads tid < ROWS (row = tid)
    int   cur = 0;
    int   ps  = 0;     // pair counter (rescale every 16 pairs = 32 steps)

    for (int c = 0; c < 64; ++c) {
        if (c) {   // next obs chunk: t in [128c, 128c+128]
            const int r = tid >> 5, ii = (tid & 31) * 4;
            *(int32x4*)&obs_lds[r][ii] =
                *(const int32x4*)(obs + (size_t)(brow0 + r) * NT + 128 * c + ii);
            if (tid < ROWS) {
                const int gi = 128 * c + 128;
                obs_lds[tid][128] = (gi < NT)
                    ? obs[(size_t)(brow0 + tid) * NT + gi] : 0;
            }
            __syncthreads();
        }
        const int npairs = (c < 63) ? 64 : 63;   // chunk 63: 63 pairs + final single
        for (int p = 0; p < npairs; ++p) {
            const int i1 = 2 * p + 1;            // t1 = 128c + 2p+1 (pair matrix)
            int o1_[4], o2_[4];
#pragma unroll
            for (int r = 0; r < 4; ++r) {
                o1_[r] = obs_lds[4 * h + r][i1];
                o2_[r] = obs_lds[4 * h + r][i1 + 1];
            }
            bf16x8 af[4];
#pragma unroll
            for (int q = 0; q < 4; ++q)
                af[q] = *(const bf16x8*)&alds[cur][SWZ(li, 32 * q + 8 * h)];

            f32x4 acc[6];
#pragma unroll
            for (int s = 0; s < 6; ++s) acc[s] = (f32x4){0.f, 0.f, 0.f, 0.f};
#pragma unroll
            for (int q = 0; q < 4; ++q)
#pragma unroll
                for (int s = 0; s < 6; ++s)
                    acc[s] = MFMA(af[q], bfrag[s][q], acc[s], 0, 0, 0);

            // select acc by row's intermediate symbol, apply final emission
            float vals[4];
#pragma unroll
            for (int r = 0; r < 4; ++r) {
                const int sy = o1_[r];
                float v = acc[0][r];
                v = (sy == 1) ? acc[1][r] : v;
                v = (sy == 2) ? acc[2][r] : v;
                v = (sy == 3) ? acc[3][r] : v;
                v = (sy == 4) ? acc[4][r] : v;
                v = (sy == 5) ? acc[5][r] : v;
                vals[r] = v * Bt[o2_[r] * NS + cc];
            }

            ++ps;
            if ((ps & 15) == 0) {   // rescale (block-uniform branch)
#pragma unroll
                for (int r = 0; r < 4; ++r) {
                    float sm = vals[r];
#pragma unroll
                    for (int off = 1; off < 16; off <<= 1) sm += __shfl_xor(sm, off);
                    if (li == 0) part[w][4 * h + r] = sm;
                }
                __syncthreads();
                if (tid < ROWS) {
                    float Z = 0.f;
#pragma unroll
                    for (int ww = 0; ww < WAVES; ++ww) Z += part[ww][tid];
                    ll += logf(Z);
                    Zs[tid] = 1.0f / Z;
                }
                __syncthreads();
#pragma unroll
                for (int r = 0; r < 4; ++r) vals[r] *= Zs[4 * h + r];
            }

#pragma unroll
            for (int r = 0; r < 4; ++r)
                alds[cur ^ 1][SWZ(4 * h + r, cc)] = f2bf(vals[r]);
            __syncthreads();
            cur ^= 1;
        }
    }

    // ---- final single step t = 8191 (chunk-63 index 127): alpha @ A, * e ----
    {
        bf16x8 af[4];
#pragma unroll
        for (int q = 0; q < 4; ++q)
            af[q] = *(const bf16x8*)&alds[cur][SWZ(li, 32 * q + 8 * h)];
        f32x4 acc = (f32x4){0.f, 0.f, 0.f, 0.f};
#pragma unroll
        for (int q = 0; q < 4; ++q) acc = MFMA(af[q], afinB[q], acc, 0, 0, 0);
#pragma unroll
        for (int r = 0; r < 4; ++r) {
            const int o = obs_lds[4 * h + r][127];
            float sm = acc[r] * Bt[o * NS + cc];
#pragma unroll
            for (int off = 1; off < 16; off <<= 1) sm += __shfl_xor(sm, off);
            if (li == 0) part[w][4 * h + r] = sm;
        }
        __syncthreads();
        if (tid < ROWS) {
            float Z = 0.f;
#pragma unroll
            for (int ww = 0; ww < WAVES; ++ww) Z += part[ww][tid];
            out[brow0 + tid] = ll + logf(Z);
        }
    }
}

// ---------------------------------------------------------------------------
// Fallback (round-7 kernel) if workspace is too small for Ct.
// ---------------------------------------------------------------------------
__global__ void __launch_bounds__(256, 1)
hmm_gemm_kernel(const int* __restrict__ obs, const float* __restrict__ I,
                const float* __restrict__ A, const float* __restrict__ Bm,
                float* __restrict__ out)
{
    __shared__ __align__(16) ushort alds[2][ROWS * NS];
    __shared__ float Bt[NE * NS];
    __shared__ __align__(16) int obs_lds[ROWS][132];
    __shared__ float part[4][ROWS];
    __shared__ float Zs[ROWS];

    const int tid = threadIdx.x;
    const int w   = tid >> 6;
    const int l   = tid & 63;
    const int h   = l >> 4;
    const int li  = l & 15;
    const int brow0 = blockIdx.x * ROWS;

    if (tid < NS) {
#pragma unroll
        for (int k = 0; k < NE; ++k) Bt[k * NS + tid] = Bm[tid * NE + k];
    }
    {
        const int r = tid >> 4, i0 = (tid & 15) * 8;
        const int32x4* g = (const int32x4*)(obs + (size_t)(brow0 + r) * NT + i0);
        *(int32x4*)&obs_lds[r][i0]     = g[0];
        *(int32x4*)&obs_lds[r][i0 + 4] = g[1];
    }
    bf16x8 bfrag[2][4];
#pragma unroll
    for (int tl = 0; tl < 2; ++tl) {
#pragma unroll
        for (int q = 0; q < 4; ++q) {
            const float* src = A + (size_t)(32 * q + 8 * h) * NS + (32 * w + 16 * tl + li);
            bf16x8 f;
#pragma unroll
            for (int j = 0; j < 8; ++j) f[j] = (short)f2bf(src[j * NS]);
            bfrag[tl][q] = f;
        }
    }
    __syncthreads();
    {
        const int r = tid >> 4, c0 = (tid & 15) * 8;
        const int o0 = obs_lds[r][0];
#pragma unroll
        for (int j = 0; j < 8; ++j) {
            const int c = c0 + j;
            alds[0][SWZ(r, c)] = f2bf(I[c] * Bt[o0 * NS + c]);
        }
    }
    __syncthreads();

    float ll = 0.f;
    int cur = 0;
    for (int t = 1; t < NT; ++t) {
        if ((t & 127) == 0) {
            const int r = tid >> 4, i0 = (tid & 15) * 8;
            const int32x4* g = (const int32x4*)(obs + (size_t)(brow0 + r) * NT + t + i0);
            *(int32x4*)&obs_lds[r][i0]     = g[0];
            *(int32x4*)&obs_lds[r][i0 + 4] = g[1];
            __syncthreads();
        }
        bf16x8 af[4];
#pragma unroll
        for (int q = 0; q < 4; ++q)
            af[q] = *(const bf16x8*)&alds[cur][SWZ(li, 32 * q + 8 * h)];
        const int tt = t & 127;
        int o[4];
#pragma unroll
        for (int r = 0; r < 4; ++r) o[r] = obs_lds[4 * h + r][tt];
        f32x4 acc[2];
        acc[0] = (f32x4){0.f, 0.f, 0.f, 0.f};
        acc[1] = (f32x4){0.f, 0.f, 0.f, 0.f};
#pragma unroll
        for (int q = 0; q < 4; ++q) {
            acc[0] = MFMA(af[q], bfrag[0][q], acc[0], 0, 0, 0);
            acc[1] = MFMA(af[q], bfrag[1][q], acc[1], 0, 0, 0);
        }
        float vals[2][4];
#pragma unroll
        for (int tl = 0; tl < 2; ++tl) {
            const int c = 32 * w + 16 * tl + li;
#pragma unroll
            for (int r = 0; r < 4; ++r) vals[tl][r] = acc[tl][r] * Bt[o[r] * NS + c];
        }
        const bool resc = ((t & 15) == 0) || (t == NT - 1);
        if (resc) {
#pragma unroll
            for (int r = 0; r < 4; ++r) {
                float s = vals[0][r] + vals[1][r];
#pragma unroll
                for (int off = 1; off < 16; off <<= 1) s += __shfl_xor(s, off);
                if (li == 0) part[w][4 * h + r] = s;
            }
            __syncthreads();
            if (tid < ROWS) {
                float Z = part[0][tid] + part[1][tid] + part[2][tid] + part[3][tid];
                ll += logf(Z);
                Zs[tid] = 1.0f / Z;
            }
            __syncthreads();
#pragma unroll
            for (int tl = 0; tl < 2; ++tl)
#pragma unroll
                for (int r = 0; r < 4; ++r) vals[tl][r] *= Zs[4 * h + r];
        }
#pragma unroll
        for (int tl = 0; tl < 2; ++tl) {
            const int c = 32 * w + 16 * tl + li;
#pragma unroll
            for (int r = 0; r < 4; ++r)
                alds[cur ^ 1][SWZ(4 * h + r, c)] = f2bf(vals[tl][r]);
        }
        __syncthreads();
        cur ^= 1;
    }
    if (tid < ROWS) out[brow0 + tid] = ll;
}

extern "C" void kernel_launch(void* const* d_in, const int* in_sizes, int n_in,
                              void* d_out, int out_size, void* d_ws, size_t ws_size,
                              hipStream_t stream) {
    (void)in_sizes; (void)n_in; (void)out_size;
    const int*   obs = (const int*)d_in[0];
    const float* I   = (const float*)d_in[1];
    const float* A   = (const float*)d_in[2];
    const float* Bm  = (const float*)d_in[3];
    float*       out = (float*)d_out;

    if (ws_size < (size_t)CT_BYTES) {
        hipLaunchKernelGGL(hmm_gemm_kernel, dim3(NB / ROWS), dim3(256), 0, stream,
                           obs, I, A, Bm, out);
        return;
    }
    ushort* Ct = (ushort*)d_ws;
    hipLaunchKernelGGL(hmm_precompute_kernel, dim3(NMAT, 4), dim3(128), 0, stream,
                       A, Bm, Ct);
    hipLaunchKernelGGL(hmm_pair6_kernel, dim3(NB / ROWS), dim3(512), 0, stream,
                       obs, I, Bm, Ct, out);
}